// Round 13
// baseline (116.679 us; speedup 1.0000x reference)
//
#include <hip/hip_runtime.h>
#include <hip/hip_bf16.h>
#include <float.h>
#include <stdint.h>

#define NPTS 8192
#define SEG  2048
#define CF   16
#define HID1 64
#define HID2 128
#define KMAX 64
#define R2   0.49f
#define CAP  384
#define NCH  6            // CAP / 64

typedef unsigned long long ULL;
typedef short bf16x8 __attribute__((ext_vector_type(8)));
typedef float f32x4  __attribute__((ext_vector_type(4)));

__device__ __forceinline__ uint32_t f2ord(float f) {
    uint32_t u = __float_as_uint(f);
    return (u & 0x80000000u) ? ~u : (u | 0x80000000u);
}

__device__ __forceinline__ short f2bf(float f) {
    __hip_bfloat16 h = __float2bfloat16(f);
    union { __hip_bfloat16 b; short s; } u; u.b = h;
    return u.s;
}

// ---- prep: A = x@W1[:16] + pos@W1[16:19] + b1 ; C = pos@W1[16:19] ;
//      pos4 = (x,y,z,sq) ; W2T[c][k] = bf16(W2[k][c]) ; echo pos/batch ----
__global__ __launch_bounds__(256) void prep_kernel(
    const float* __restrict__ x, const float* __restrict__ pos,
    const int* __restrict__ batch,
    const float* __restrict__ W1, const float* __restrict__ b1,
    const float* __restrict__ W2,
    float* __restrict__ A, float* __restrict__ C,
    float4* __restrict__ pos4, unsigned short* __restrict__ W2T,
    float* __restrict__ out)
{
    const int t = blockIdx.x * 256 + threadIdx.x;   // t < NPTS*64
    const int i = t >> 6, k = t & 63;

    const float px = pos[3 * i + 0], py = pos[3 * i + 1], pz = pos[3 * i + 2];
    float c = __fmul_rn(px, W1[16 * HID1 + k]);
    c = fmaf(py, W1[17 * HID1 + k], c);
    c = fmaf(pz, W1[18 * HID1 + k], c);

    float a = b1[k];
    #pragma unroll
    for (int cc = 0; cc < CF; ++cc)
        a = fmaf(x[i * CF + cc], W1[cc * HID1 + k], a);
    a += c;

    A[t] = a;
    C[t] = c;

    if (t < HID1 * HID2) {
        const int cc = t >> 6, kk = t & 63;      // W2T[c][k], c-stride 64
        W2T[t] = (unsigned short)f2bf(W2[kk * HID2 + cc]);
    }

    if (k == 0) {
        const float sq = __fadd_rn(__fadd_rn(__fmul_rn(px, px), __fmul_rn(py, py)),
                                   __fmul_rn(pz, pz));
        pos4[i] = make_float4(px, py, pz, sq);
    }
    if (k < 3) out[NPTS * HID2 + 3 * i + k] = pos[3 * i + k];
    if (k == 3) out[NPTS * HID2 + NPTS * 3 + i] = (float)batch[i];
}

// ---- 1 wave = 4 centroids. PHASE: 1 = scan only, 2 = scan+select, 3 = full.
//      Probes (1,2) write keep-alive sinks; 3 writes out. ----
template<int PHASE>
__global__ __launch_bounds__(64, 3) void pc(
    const int* __restrict__ batch,
    const unsigned short* __restrict__ W2T, const float* __restrict__ b2,
    const float* __restrict__ A, const float* __restrict__ C,
    const float4* __restrict__ pos4, float* __restrict__ out,
    int* __restrict__ sink)
{
    __shared__ ULL s_key[4][CAP];   // 12 KB
    __shared__ int s_nbr[4][KMAX];  // 1 KB

    const int l  = threadIdx.x;
    const int i0 = blockIdx.x * 4;          // 4 centroids, same segment
    const ULL lmask = (1ull << l) - 1ull;

    float4 cw[4];
    #pragma unroll
    for (int ci = 0; ci < 4; ++ci) cw[ci] = pos4[i0 + ci];
    const int seg0 = batch[i0] * SEG;

    // ---- scan: each point loaded once, tested vs 4 centroids ----
    int cnt[4] = {0, 0, 0, 0};
    #pragma unroll 2
    for (int it = 0; it < SEG / 64; ++it) {
        const int j = seg0 + it * 64 + l;
        const float4 pj = pos4[j];
        #pragma unroll
        for (int ci = 0; ci < 4; ++ci) {
            const float dot = fmaf(cw[ci].z, pj.z,
                              fmaf(cw[ci].y, pj.y, __fmul_rn(cw[ci].x, pj.x)));
            const float d2  = __fsub_rn(__fadd_rn(cw[ci].w, pj.w), __fmul_rn(2.0f, dot));
            const bool hit = (d2 <= R2);
            const ULL mk = __ballot(hit);
            if (hit) {
                const int p = cnt[ci] + __popcll(mk & lmask);
                if (p < CAP) s_key[ci][p] = ((ULL)f2ord(d2) << 32) | (unsigned)j;
            }
            cnt[ci] += __popcll(mk);
        }
    }
    #pragma unroll
    for (int ci = 0; ci < 4; ++ci) if (cnt[ci] > CAP) cnt[ci] = CAP;

    if constexpr (PHASE == 1) {
        if (l == 0) {
            #pragma unroll
            for (int ci = 0; ci < 4; ++ci) sink[blockIdx.x * 4 + ci] = cnt[ci];
        }
        return;
    }

    // ---- select: exact threshold top-K, 4 interleaved chains ----
    bool nd[4];
    #pragma unroll
    for (int ci = 0; ci < 4; ++ci) nd[ci] = cnt[ci] > KMAX;

    uint32_t eo[4][NCH], ej[4][NCH];
    #pragma unroll
    for (int ci = 0; ci < 4; ++ci) {
        if (!nd[ci]) {
            if (l < KMAX)
                s_nbr[ci][l] = (l < cnt[ci]) ? (int)(s_key[ci][l] & 0xffffffffu) : i0 + ci;
        } else {
            #pragma unroll
            for (int g = 0; g < NCH; ++g) {
                eo[ci][g] = 0xffffffffu; ej[ci][g] = 0xffffffffu;
                if (64 * g < cnt[ci]) {
                    const int e = l + 64 * g;
                    if (e < cnt[ci]) {
                        const ULL kk = s_key[ci][e];
                        eo[ci][g] = (uint32_t)(kk >> 32);
                        ej[ci][g] = (uint32_t)(kk & 0xffffffffu);
                    }
                }
            }
        }
    }

    if (nd[0] | nd[1] | nd[2] | nd[3]) {
        const uint32_t ORDR2 = 0x80000000u | __float_as_uint(R2);
        uint32_t lo[4], hi[4];
        #pragma unroll
        for (int ci = 0; ci < 4; ++ci) { lo[ci] = 0u; hi[ci] = nd[ci] ? ORDR2 : 0u; }
        while ((lo[0] < hi[0]) | (lo[1] < hi[1]) | (lo[2] < hi[2]) | (lo[3] < hi[3])) {
            #pragma unroll
            for (int ci = 0; ci < 4; ++ci) {
                if (lo[ci] < hi[ci]) {
                    const uint32_t mid = lo[ci] + ((hi[ci] - lo[ci]) >> 1);
                    int c = 0;
                    #pragma unroll
                    for (int g = 0; g < NCH; ++g)
                        if (64 * g < cnt[ci]) c += __popcll(__ballot(eo[ci][g] <= mid));
                    if (c >= KMAX) hi[ci] = mid; else lo[ci] = mid + 1;
                }
            }
        }

        int cLT[4] = {0,0,0,0}, cLE[4] = {0,0,0,0};
        #pragma unroll
        for (int ci = 0; ci < 4; ++ci) {
            if (nd[ci]) {
                #pragma unroll
                for (int g = 0; g < NCH; ++g) {
                    cLT[ci] += __popcll(__ballot(eo[ci][g] < lo[ci]));
                    cLE[ci] += __popcll(__ballot(eo[ci][g] <= lo[ci]));
                }
            }
        }

        // tie resolution on j (exact; rarely taken)
        uint32_t J[4]; bool tb[4];
        #pragma unroll
        for (int ci = 0; ci < 4; ++ci) {
            J[ci] = 0xffffffffu;
            tb[ci] = nd[ci] && (cLE[ci] > KMAX);
        }
        if (tb[0] | tb[1] | tb[2] | tb[3]) {
            uint32_t jlo[4], jhi[4];
            #pragma unroll
            for (int ci = 0; ci < 4; ++ci) { jlo[ci] = 0u; jhi[ci] = tb[ci] ? (NPTS - 1) : 0u; }
            while ((jlo[0] < jhi[0]) | (jlo[1] < jhi[1]) | (jlo[2] < jhi[2]) | (jlo[3] < jhi[3])) {
                #pragma unroll
                for (int ci = 0; ci < 4; ++ci) {
                    if (jlo[ci] < jhi[ci]) {
                        const uint32_t jmid = jlo[ci] + ((jhi[ci] - jlo[ci]) >> 1);
                        int c = 0;
                        #pragma unroll
                        for (int g = 0; g < NCH; ++g)
                            if (64 * g < cnt[ci])
                                c += __popcll(__ballot(eo[ci][g] == lo[ci] && ej[ci][g] <= jmid));
                        if (c >= KMAX - cLT[ci]) jhi[ci] = jmid; else jlo[ci] = jmid + 1;
                    }
                }
            }
            #pragma unroll
            for (int ci = 0; ci < 4; ++ci) if (tb[ci]) J[ci] = jlo[ci];
        }

        #pragma unroll
        for (int ci = 0; ci < 4; ++ci) {
            if (nd[ci]) {
                int sb = 0;
                #pragma unroll
                for (int g = 0; g < NCH; ++g) {
                    if (64 * g < cnt[ci]) {
                        const bool take = (eo[ci][g] < lo[ci]) ||
                                          ((eo[ci][g] == lo[ci]) && (ej[ci][g] <= J[ci]));
                        const ULL mk = __ballot(take);
                        if (take) s_nbr[ci][sb + __popcll(mk & lmask)] = (int)ej[ci][g];
                        sb += __popcll(mk);
                    }
                }
            }
        }
    }

    if constexpr (PHASE == 2) {
        // keep all 4 chains live
        sink[blockIdx.x * 64 + l] =
            s_nbr[0][l] ^ s_nbr[1][l] ^ s_nbr[2][l] ^ s_nbr[3][l];
        return;
    }

    // ---- MFMA phase: 2 centroid-pairs, hoisted af build, shared-B MFMA ----
    const int r = l & 15, q = l >> 4;
    int mm[4];
    #pragma unroll
    for (int ci = 0; ci < 4; ++ci) mm[ci] = cnt[ci] < KMAX ? cnt[ci] : KMAX;

    #pragma unroll
    for (int pp = 0; pp < 2; ++pp) {
        bf16x8 af[2][4][2];
        #pragma unroll
        for (int cip = 0; cip < 2; ++cip) {
            const int ci = pp * 2 + cip;
            const int iw = i0 + ci;
            float cv[2][8];
            {
                const float4* Cv = (const float4*)(C + (size_t)iw * HID1);
                #pragma unroll
                for (int kc = 0; kc < 2; ++kc) {
                    const float4 c0 = Cv[kc * 8 + q * 2], c1 = Cv[kc * 8 + q * 2 + 1];
                    cv[kc][0] = c0.x; cv[kc][1] = c0.y; cv[kc][2] = c0.z; cv[kc][3] = c0.w;
                    cv[kc][4] = c1.x; cv[kc][5] = c1.y; cv[kc][6] = c1.z; cv[kc][7] = c1.w;
                }
            }
            #pragma unroll
            for (int t = 0; t < 4; ++t) {
                const int row = t * 16 + r;
                const int j = s_nbr[ci][row];
                const float4* Aj = (const float4*)(A + (size_t)j * HID1);
                #pragma unroll
                for (int kc = 0; kc < 2; ++kc) {
                    const float4 a0 = Aj[kc * 8 + q * 2], a1 = Aj[kc * 8 + q * 2 + 1];
                    bf16x8 v;
                    v[0] = f2bf(fmaxf(a0.x - cv[kc][0], 0.0f));
                    v[1] = f2bf(fmaxf(a0.y - cv[kc][1], 0.0f));
                    v[2] = f2bf(fmaxf(a0.z - cv[kc][2], 0.0f));
                    v[3] = f2bf(fmaxf(a0.w - cv[kc][3], 0.0f));
                    v[4] = f2bf(fmaxf(a1.x - cv[kc][4], 0.0f));
                    v[5] = f2bf(fmaxf(a1.y - cv[kc][5], 0.0f));
                    v[6] = f2bf(fmaxf(a1.z - cv[kc][6], 0.0f));
                    v[7] = f2bf(fmaxf(a1.w - cv[kc][7], 0.0f));
                    af[cip][t][kc] = v;
                }
            }
        }

        #pragma unroll
        for (int cb = 0; cb < 8; ++cb) {
            f32x4 acc[2][4];
            #pragma unroll
            for (int cip = 0; cip < 2; ++cip)
                #pragma unroll
                for (int t = 0; t < 4; ++t) acc[cip][t] = (f32x4){0.f, 0.f, 0.f, 0.f};

            #pragma unroll
            for (int kc = 0; kc < 2; ++kc) {
                const bf16x8 bf =
                    *(const bf16x8*)&W2T[(cb * 16 + r) * HID1 + kc * 32 + q * 8];
                #pragma unroll
                for (int cip = 0; cip < 2; ++cip)
                    #pragma unroll
                    for (int t = 0; t < 4; ++t)
                        acc[cip][t] = __builtin_amdgcn_mfma_f32_16x16x32_bf16(
                            af[cip][t][kc], bf, acc[cip][t], 0, 0, 0);
            }

            const int c = cb * 16 + r;
            #pragma unroll
            for (int cip = 0; cip < 2; ++cip) {
                const int ci = pp * 2 + cip;
                float v = -FLT_MAX;
                #pragma unroll
                for (int t = 0; t < 4; ++t) {
                    const int nb = t * 16 + q * 4;  // D: col=l&15, row=(l>>4)*4+reg
                    #pragma unroll
                    for (int reg = 0; reg < 4; ++reg)
                        if (nb + reg < mm[ci]) v = fmaxf(v, acc[cip][t][reg]);
                }
                v = fmaxf(v, __shfl_xor(v, 16));
                v = fmaxf(v, __shfl_xor(v, 32));
                if (q == 0)
                    out[(size_t)(i0 + ci) * HID2 + c] = fmaxf(v + b2[c], 0.0f);
            }
        }
    }
}

extern "C" void kernel_launch(void* const* d_in, const int* in_sizes, int n_in,
                              void* d_out, int out_size, void* d_ws, size_t ws_size,
                              hipStream_t stream) {
    const float* x     = (const float*)d_in[0];
    const float* pos   = (const float*)d_in[1];
    const int*   batch = (const int*)d_in[2];
    const float* W1    = (const float*)d_in[3];
    const float* b1    = (const float*)d_in[4];
    const float* W2    = (const float*)d_in[5];
    const float* b2    = (const float*)d_in[6];
    float* out = (float*)d_out;

    float*  A    = (float*)d_ws;                          // 2 MB
    float*  C    = A + (size_t)NPTS * HID1;               // 2 MB
    float4* P4   = (float4*)(C + (size_t)NPTS * HID1);    // 128 KB
    unsigned short* W2T = (unsigned short*)(P4 + NPTS);   // 16 KB
    int* sink1 = (int*)(W2T + HID1 * HID2);               // 32 KB
    int* sink2 = sink1 + NPTS;                            // 512 KB

    hipLaunchKernelGGL(prep_kernel, dim3(NPTS * HID1 / 256), dim3(256), 0, stream,
                       x, pos, batch, W1, b1, W2, A, C, P4, W2T, out);
    // probes (phase ablation; read durations from rocprof dispatch table)
    hipLaunchKernelGGL(pc<1>, dim3(NPTS / 4), dim3(64), 0, stream,
                       batch, W2T, b2, A, C, P4, out, sink1);
    hipLaunchKernelGGL(pc<2>, dim3(NPTS / 4), dim3(64), 0, stream,
                       batch, W2T, b2, A, C, P4, out, sink2);
    // the real kernel
    hipLaunchKernelGGL(pc<3>, dim3(NPTS / 4), dim3(64), 0, stream,
                       batch, W2T, b2, A, C, P4, out, sink1);
}

// Round 14
// 71.915 us; speedup vs baseline: 1.6225x; 1.6225x over previous
//
#include <hip/hip_runtime.h>
#include <hip/hip_bf16.h>
#include <float.h>
#include <stdint.h>

#define NPTS 8192
#define SEG  2048
#define CF   16
#define HID1 64
#define HID2 128
#define KMAX 64
#define R2   0.49f
#define CAP  384
#define NCH  6            // CAP / 64

typedef unsigned long long ULL;
typedef short bf16x8 __attribute__((ext_vector_type(8)));
typedef float f32x4  __attribute__((ext_vector_type(4)));

__device__ __forceinline__ uint32_t f2ord(float f) {
    uint32_t u = __float_as_uint(f);
    return (u & 0x80000000u) ? ~u : (u | 0x80000000u);
}

__device__ __forceinline__ short f2bf(float f) {
    __hip_bfloat16 h = __float2bfloat16(f);
    union { __hip_bfloat16 b; short s; } u; u.b = h;
    return u.s;
}

// ---- prep: A = x@W1[:16] + pos@W1[16:19] + b1 ; C = pos@W1[16:19] ;
//      pos4 = (x,y,z,sq) ; W2T[c][k] = bf16(W2[k][c]) ; echo pos/batch ----
__global__ __launch_bounds__(256) void prep_kernel(
    const float* __restrict__ x, const float* __restrict__ pos,
    const int* __restrict__ batch,
    const float* __restrict__ W1, const float* __restrict__ b1,
    const float* __restrict__ W2,
    float* __restrict__ A, float* __restrict__ C,
    float4* __restrict__ pos4, unsigned short* __restrict__ W2T,
    float* __restrict__ out)
{
    const int t = blockIdx.x * 256 + threadIdx.x;   // t < NPTS*64
    const int i = t >> 6, k = t & 63;

    const float px = pos[3 * i + 0], py = pos[3 * i + 1], pz = pos[3 * i + 2];
    float c = __fmul_rn(px, W1[16 * HID1 + k]);
    c = fmaf(py, W1[17 * HID1 + k], c);
    c = fmaf(pz, W1[18 * HID1 + k], c);

    float a = b1[k];
    #pragma unroll
    for (int cc = 0; cc < CF; ++cc)
        a = fmaf(x[i * CF + cc], W1[cc * HID1 + k], a);
    a += c;

    A[t] = a;
    C[t] = c;

    if (t < HID1 * HID2) {
        const int cc = t >> 6, kk = t & 63;      // W2T[c][k], c-stride 64
        W2T[t] = (unsigned short)f2bf(W2[kk * HID2 + cc]);
    }

    if (k == 0) {
        const float sq = __fadd_rn(__fadd_rn(__fmul_rn(px, px), __fmul_rn(py, py)),
                                   __fmul_rn(pz, pz));
        pos4[i] = make_float4(px, py, pz, sq);
    }
    if (k < 3) out[NPTS * HID2 + 3 * i + k] = pos[3 * i + k];
    if (k == 3) out[NPTS * HID2 + NPTS * 3 + i] = (float)batch[i];
}

// ---- block = 2 waves, 4 centroids. Each wave scans HALF the segment for all
//      4 centroids (LDS-atomic append, order-free); 1 barrier; then wave w
//      selects + MFMAs centroids {2w, 2w+1} exactly as r12 (wave-local). ----
__global__ __launch_bounds__(128, 3) void pointconv_kernel(
    const int* __restrict__ batch,
    const unsigned short* __restrict__ W2T, const float* __restrict__ b2,
    const float* __restrict__ A, const float* __restrict__ C,
    const float4* __restrict__ pos4, float* __restrict__ out)
{
    __shared__ ULL s_key[4][CAP];   // 12 KB
    __shared__ int s_nbr[4][KMAX];  // 1 KB
    __shared__ int s_cnt[4];

    const int tid = threadIdx.x;
    const int w   = tid >> 6, l = tid & 63;
    const int i0  = blockIdx.x * 4;          // 4 centroids, same segment
    const ULL lmask = (1ull << l) - 1ull;

    if (tid < 4) s_cnt[tid] = 0;

    float4 cw[4];
    #pragma unroll
    for (int ci = 0; ci < 4; ++ci) cw[ci] = pos4[i0 + ci];
    const int seg0 = batch[i0] * SEG;
    __syncthreads();

    // ---- scan: wave w covers points [w*1024, (w+1)*1024) for all 4 centroids
    const int base = seg0 + w * (SEG / 2);
    #pragma unroll 2
    for (int it = 0; it < SEG / 128; ++it) {
        const int j = base + it * 64 + l;
        const float4 pj = pos4[j];
        #pragma unroll
        for (int ci = 0; ci < 4; ++ci) {
            const float dot = fmaf(cw[ci].z, pj.z,
                              fmaf(cw[ci].y, pj.y, __fmul_rn(cw[ci].x, pj.x)));
            const float d2  = __fsub_rn(__fadd_rn(cw[ci].w, pj.w), __fmul_rn(2.0f, dot));
            if (d2 <= R2) {
                const int p = atomicAdd(&s_cnt[ci], 1);
                if (p < CAP)
                    s_key[ci][p] = ((ULL)f2ord(d2) << 32) | (unsigned)j;
            }
        }
    }
    __syncthreads();   // only barrier; below is wave-local

    // ---- wave w owns centroids c0 = 2w, c1 = 2w+1 ----
    const int c0i = 2 * w, c1i = 2 * w + 1;
    int cnt0 = s_cnt[c0i], cnt1 = s_cnt[c1i];
    if (cnt0 > CAP) cnt0 = CAP;
    if (cnt1 > CAP) cnt1 = CAP;
    const bool nd0 = cnt0 > KMAX, nd1 = cnt1 > KMAX;

    uint32_t eo0[NCH], ej0[NCH], eo1[NCH], ej1[NCH];
    if (!nd0) {
        if (l < KMAX) s_nbr[c0i][l] = (l < cnt0) ? (int)(s_key[c0i][l] & 0xffffffffu) : i0 + c0i;
    } else {
        #pragma unroll
        for (int g = 0; g < NCH; ++g) {
            eo0[g] = 0xffffffffu; ej0[g] = 0xffffffffu;
            if (64 * g < cnt0) {
                const int e = l + 64 * g;
                if (e < cnt0) {
                    const ULL kk = s_key[c0i][e];
                    eo0[g] = (uint32_t)(kk >> 32);
                    ej0[g] = (uint32_t)(kk & 0xffffffffu);
                }
            }
        }
    }
    if (!nd1) {
        if (l < KMAX) s_nbr[c1i][l] = (l < cnt1) ? (int)(s_key[c1i][l] & 0xffffffffu) : i0 + c1i;
    } else {
        #pragma unroll
        for (int g = 0; g < NCH; ++g) {
            eo1[g] = 0xffffffffu; ej1[g] = 0xffffffffu;
            if (64 * g < cnt1) {
                const int e = l + 64 * g;
                if (e < cnt1) {
                    const ULL kk = s_key[c1i][e];
                    eo1[g] = (uint32_t)(kk >> 32);
                    ej1[g] = (uint32_t)(kk & 0xffffffffu);
                }
            }
        }
    }

    if (nd0 || nd1) {
        const uint32_t ORDR2 = 0x80000000u | __float_as_uint(R2);
        uint32_t lo0 = 0u, hi0 = nd0 ? ORDR2 : 0u;
        uint32_t lo1 = 0u, hi1 = nd1 ? ORDR2 : 0u;
        while ((lo0 < hi0) | (lo1 < hi1)) {
            if (lo0 < hi0) {
                const uint32_t mid = lo0 + ((hi0 - lo0) >> 1);
                int c = 0;
                #pragma unroll
                for (int g = 0; g < NCH; ++g)
                    if (64 * g < cnt0) c += __popcll(__ballot(eo0[g] <= mid));
                if (c >= KMAX) hi0 = mid; else lo0 = mid + 1;
            }
            if (lo1 < hi1) {
                const uint32_t mid = lo1 + ((hi1 - lo1) >> 1);
                int c = 0;
                #pragma unroll
                for (int g = 0; g < NCH; ++g)
                    if (64 * g < cnt1) c += __popcll(__ballot(eo1[g] <= mid));
                if (c >= KMAX) hi1 = mid; else lo1 = mid + 1;
            }
        }
        const uint32_t T0 = lo0, T1 = lo1;

        int cLT0 = 0, cLE0 = 0, cLT1 = 0, cLE1 = 0;
        if (nd0) {
            #pragma unroll
            for (int g = 0; g < NCH; ++g) {
                cLT0 += __popcll(__ballot(eo0[g] < T0));
                cLE0 += __popcll(__ballot(eo0[g] <= T0));
            }
        }
        if (nd1) {
            #pragma unroll
            for (int g = 0; g < NCH; ++g) {
                cLT1 += __popcll(__ballot(eo1[g] < T1));
                cLE1 += __popcll(__ballot(eo1[g] <= T1));
            }
        }

        uint32_t J0 = 0xffffffffu, J1 = 0xffffffffu;
        const bool tb0 = nd0 && (cLE0 > KMAX), tb1 = nd1 && (cLE1 > KMAX);
        if (tb0 | tb1) {
            uint32_t jlo0 = 0u, jhi0 = tb0 ? (NPTS - 1) : 0u;
            uint32_t jlo1 = 0u, jhi1 = tb1 ? (NPTS - 1) : 0u;
            const int need0 = KMAX - cLT0, need1 = KMAX - cLT1;
            while ((jlo0 < jhi0) | (jlo1 < jhi1)) {
                if (jlo0 < jhi0) {
                    const uint32_t jmid = jlo0 + ((jhi0 - jlo0) >> 1);
                    int c = 0;
                    #pragma unroll
                    for (int g = 0; g < NCH; ++g)
                        if (64 * g < cnt0) c += __popcll(__ballot(eo0[g] == T0 && ej0[g] <= jmid));
                    if (c >= need0) jhi0 = jmid; else jlo0 = jmid + 1;
                }
                if (jlo1 < jhi1) {
                    const uint32_t jmid = jlo1 + ((jhi1 - jlo1) >> 1);
                    int c = 0;
                    #pragma unroll
                    for (int g = 0; g < NCH; ++g)
                        if (64 * g < cnt1) c += __popcll(__ballot(eo1[g] == T1 && ej1[g] <= jmid));
                    if (c >= need1) jhi1 = jmid; else jlo1 = jmid + 1;
                }
            }
            if (tb0) J0 = jlo0;
            if (tb1) J1 = jlo1;
        }

        if (nd0) {
            int sb = 0;
            #pragma unroll
            for (int g = 0; g < NCH; ++g) {
                if (64 * g < cnt0) {
                    const bool take = (eo0[g] < T0) || ((eo0[g] == T0) && (ej0[g] <= J0));
                    const ULL mk = __ballot(take);
                    if (take) s_nbr[c0i][sb + __popcll(mk & lmask)] = (int)ej0[g];
                    sb += __popcll(mk);
                }
            }
        }
        if (nd1) {
            int sb = 0;
            #pragma unroll
            for (int g = 0; g < NCH; ++g) {
                if (64 * g < cnt1) {
                    const bool take = (eo1[g] < T1) || ((eo1[g] == T1) && (ej1[g] <= J1));
                    const ULL mk = __ballot(take);
                    if (take) s_nbr[c1i][sb + __popcll(mk & lmask)] = (int)ej1[g];
                    sb += __popcll(mk);
                }
            }
        }
    }

    // ---- MFMA phase: this wave's 2 centroids, hoisted af build, shared-B ----
    const int r = l & 15, q = l >> 4;
    const int mm[2] = { cnt0 < KMAX ? cnt0 : KMAX, cnt1 < KMAX ? cnt1 : KMAX };

    bf16x8 af[2][4][2];
    #pragma unroll
    for (int cip = 0; cip < 2; ++cip) {
        const int ci = 2 * w + cip;
        const int iw = i0 + ci;
        float cv[2][8];
        {
            const float4* Cv = (const float4*)(C + (size_t)iw * HID1);
            #pragma unroll
            for (int kc = 0; kc < 2; ++kc) {
                const float4 c0 = Cv[kc * 8 + q * 2], c1 = Cv[kc * 8 + q * 2 + 1];
                cv[kc][0] = c0.x; cv[kc][1] = c0.y; cv[kc][2] = c0.z; cv[kc][3] = c0.w;
                cv[kc][4] = c1.x; cv[kc][5] = c1.y; cv[kc][6] = c1.z; cv[kc][7] = c1.w;
            }
        }
        #pragma unroll
        for (int t = 0; t < 4; ++t) {
            const int row = t * 16 + r;
            const int j = s_nbr[ci][row];      // valid index even for row >= m
            const float4* Aj = (const float4*)(A + (size_t)j * HID1);
            #pragma unroll
            for (int kc = 0; kc < 2; ++kc) {
                const float4 a0 = Aj[kc * 8 + q * 2], a1 = Aj[kc * 8 + q * 2 + 1];
                bf16x8 v;
                v[0] = f2bf(fmaxf(a0.x - cv[kc][0], 0.0f));
                v[1] = f2bf(fmaxf(a0.y - cv[kc][1], 0.0f));
                v[2] = f2bf(fmaxf(a0.z - cv[kc][2], 0.0f));
                v[3] = f2bf(fmaxf(a0.w - cv[kc][3], 0.0f));
                v[4] = f2bf(fmaxf(a1.x - cv[kc][4], 0.0f));
                v[5] = f2bf(fmaxf(a1.y - cv[kc][5], 0.0f));
                v[6] = f2bf(fmaxf(a1.z - cv[kc][6], 0.0f));
                v[7] = f2bf(fmaxf(a1.w - cv[kc][7], 0.0f));
                af[cip][t][kc] = v;
            }
        }
    }

    #pragma unroll
    for (int cb = 0; cb < 8; ++cb) {
        f32x4 acc[2][4];
        #pragma unroll
        for (int cip = 0; cip < 2; ++cip)
            #pragma unroll
            for (int t = 0; t < 4; ++t) acc[cip][t] = (f32x4){0.f, 0.f, 0.f, 0.f};

        #pragma unroll
        for (int kc = 0; kc < 2; ++kc) {
            const bf16x8 bf =
                *(const bf16x8*)&W2T[(cb * 16 + r) * HID1 + kc * 32 + q * 8];
            #pragma unroll
            for (int cip = 0; cip < 2; ++cip)
                #pragma unroll
                for (int t = 0; t < 4; ++t)
                    acc[cip][t] = __builtin_amdgcn_mfma_f32_16x16x32_bf16(
                        af[cip][t][kc], bf, acc[cip][t], 0, 0, 0);
        }

        const int c = cb * 16 + r;
        #pragma unroll
        for (int cip = 0; cip < 2; ++cip) {
            float v = -FLT_MAX;
            #pragma unroll
            for (int t = 0; t < 4; ++t) {
                const int nb = t * 16 + q * 4; // D: col=l&15, row=(l>>4)*4+reg
                #pragma unroll
                for (int reg = 0; reg < 4; ++reg)
                    if (nb + reg < mm[cip]) v = fmaxf(v, acc[cip][t][reg]);
            }
            v = fmaxf(v, __shfl_xor(v, 16));
            v = fmaxf(v, __shfl_xor(v, 32));
            if (q == 0)
                out[(size_t)(i0 + 2 * w + cip) * HID2 + c] = fmaxf(v + b2[c], 0.0f);
        }
    }
}

extern "C" void kernel_launch(void* const* d_in, const int* in_sizes, int n_in,
                              void* d_out, int out_size, void* d_ws, size_t ws_size,
                              hipStream_t stream) {
    const float* x     = (const float*)d_in[0];
    const float* pos   = (const float*)d_in[1];
    const int*   batch = (const int*)d_in[2];
    const float* W1    = (const float*)d_in[3];
    const float* b1    = (const float*)d_in[4];
    const float* W2    = (const float*)d_in[5];
    const float* b2    = (const float*)d_in[6];
    float* out = (float*)d_out;

    float*  A    = (float*)d_ws;                          // 2 MB
    float*  C    = A + (size_t)NPTS * HID1;               // 2 MB
    float4* P4   = (float4*)(C + (size_t)NPTS * HID1);    // 128 KB
    unsigned short* W2T = (unsigned short*)(P4 + NPTS);   // 16 KB

    hipLaunchKernelGGL(prep_kernel, dim3(NPTS * HID1 / 256), dim3(256), 0, stream,
                       x, pos, batch, W1, b1, W2, A, C, P4, W2T, out);
    hipLaunchKernelGGL(pointconv_kernel, dim3(NPTS / 4), dim3(128), 0, stream,
                       batch, W2T, b2, A, C, P4, out);
}

// Round 15
// 65.793 us; speedup vs baseline: 1.7734x; 1.0931x over previous
//
#include <hip/hip_runtime.h>
#include <hip/hip_bf16.h>
#include <float.h>
#include <stdint.h>

#define NPTS 8192
#define SEG  2048
#define CF   16
#define HID1 64
#define HID2 128
#define KMAX 64
#define R2   0.49f
#define CAP  384
#define NCH  6            // CAP / 64

typedef unsigned long long ULL;
typedef short bf16x8 __attribute__((ext_vector_type(8)));
typedef float f32x4  __attribute__((ext_vector_type(4)));

__device__ __forceinline__ uint32_t f2ord(float f) {
    uint32_t u = __float_as_uint(f);
    return (u & 0x80000000u) ? ~u : (u | 0x80000000u);
}

__device__ __forceinline__ short f2bf(float f) {
    __hip_bfloat16 h = __float2bfloat16(f);
    union { __hip_bfloat16 b; short s; } u; u.b = h;
    return u.s;
}

// ---- prep: A = x@W1[:16] + pos@W1[16:19] + b1 ; C = pos@W1[16:19] ;
//      pos4 = (x,y,z,sq) ; W2T[c][k] = bf16(W2[k][c]) ; echo pos/batch ----
__global__ __launch_bounds__(256) void prep_kernel(
    const float* __restrict__ x, const float* __restrict__ pos,
    const int* __restrict__ batch,
    const float* __restrict__ W1, const float* __restrict__ b1,
    const float* __restrict__ W2,
    float* __restrict__ A, float* __restrict__ C,
    float4* __restrict__ pos4, unsigned short* __restrict__ W2T,
    float* __restrict__ out)
{
    const int t = blockIdx.x * 256 + threadIdx.x;   // t < NPTS*64
    const int i = t >> 6, k = t & 63;

    const float px = pos[3 * i + 0], py = pos[3 * i + 1], pz = pos[3 * i + 2];
    float c = __fmul_rn(px, W1[16 * HID1 + k]);
    c = fmaf(py, W1[17 * HID1 + k], c);
    c = fmaf(pz, W1[18 * HID1 + k], c);

    float a = b1[k];
    #pragma unroll
    for (int cc = 0; cc < CF; ++cc)
        a = fmaf(x[i * CF + cc], W1[cc * HID1 + k], a);
    a += c;

    A[t] = a;
    C[t] = c;

    if (t < HID1 * HID2) {
        const int cc = t >> 6, kk = t & 63;      // W2T[c][k], c-stride 64
        W2T[t] = (unsigned short)f2bf(W2[kk * HID2 + cc]);
    }

    if (k == 0) {
        const float sq = __fadd_rn(__fadd_rn(__fmul_rn(px, px), __fmul_rn(py, py)),
                                   __fmul_rn(pz, pz));
        pos4[i] = make_float4(px, py, pz, sq);
    }
    if (k < 3) out[NPTS * HID2 + 3 * i + k] = pos[3 * i + k];
    if (k == 3) out[NPTS * HID2 + NPTS * 3 + i] = (float)batch[i];
}

// ---- phase 1: 1 wave = 2 centroids, scan + exact threshold top-K ->
//      nbr[i][64] + mcnt[i] to global. Low VGPR (no MFMA state) -> (64,6). ----
__global__ __launch_bounds__(64, 6) void select_kernel(
    const int* __restrict__ batch, const float4* __restrict__ pos4,
    int* __restrict__ nbr, int* __restrict__ mcnt)
{
    __shared__ ULL s_key[2][CAP];   // 6 KB

    const int l  = threadIdx.x;
    const int i0 = blockIdx.x * 2;          // pair shares a segment (2048 even)

    const float4 cw0 = pos4[i0], cw1 = pos4[i0 + 1];
    const int seg0 = batch[i0] * SEG;
    const ULL lmask = (1ull << l) - 1ull;

    // shared-load scan: each point loaded once, tested vs both centroids
    int cnt0 = 0, cnt1 = 0;
    #pragma unroll 4
    for (int it = 0; it < SEG / 64; ++it) {
        const int j = seg0 + it * 64 + l;
        const float4 pj = pos4[j];
        const float dot0 = fmaf(cw0.z, pj.z, fmaf(cw0.y, pj.y, __fmul_rn(cw0.x, pj.x)));
        const float d20  = __fsub_rn(__fadd_rn(cw0.w, pj.w), __fmul_rn(2.0f, dot0));
        const float dot1 = fmaf(cw1.z, pj.z, fmaf(cw1.y, pj.y, __fmul_rn(cw1.x, pj.x)));
        const float d21  = __fsub_rn(__fadd_rn(cw1.w, pj.w), __fmul_rn(2.0f, dot1));
        const bool h0 = (d20 <= R2), h1 = (d21 <= R2);
        const ULL m0 = __ballot(h0), m1 = __ballot(h1);
        if (h0) {
            const int p = cnt0 + __popcll(m0 & lmask);
            if (p < CAP) s_key[0][p] = ((ULL)f2ord(d20) << 32) | (unsigned)j;
        }
        cnt0 += __popcll(m0);
        if (h1) {
            const int p = cnt1 + __popcll(m1 & lmask);
            if (p < CAP) s_key[1][p] = ((ULL)f2ord(d21) << 32) | (unsigned)j;
        }
        cnt1 += __popcll(m1);
    }
    if (cnt0 > CAP) cnt0 = CAP;
    if (cnt1 > CAP) cnt1 = CAP;
    const bool nd0 = cnt0 > KMAX, nd1 = cnt1 > KMAX;

    if (l == 0) {
        mcnt[i0]     = cnt0 < KMAX ? cnt0 : KMAX;
        mcnt[i0 + 1] = cnt1 < KMAX ? cnt1 : KMAX;
    }

    uint32_t eo0[NCH], ej0[NCH], eo1[NCH], ej1[NCH];
    if (!nd0) {
        if (l < KMAX)
            nbr[(size_t)i0 * KMAX + l] = (l < cnt0) ? (int)(s_key[0][l] & 0xffffffffu) : i0;
    } else {
        #pragma unroll
        for (int g = 0; g < NCH; ++g) {
            eo0[g] = 0xffffffffu; ej0[g] = 0xffffffffu;
            if (64 * g < cnt0) {
                const int e = l + 64 * g;
                if (e < cnt0) {
                    const ULL kk = s_key[0][e];
                    eo0[g] = (uint32_t)(kk >> 32);
                    ej0[g] = (uint32_t)(kk & 0xffffffffu);
                }
            }
        }
    }
    if (!nd1) {
        if (l < KMAX)
            nbr[(size_t)(i0 + 1) * KMAX + l] = (l < cnt1) ? (int)(s_key[1][l] & 0xffffffffu) : i0 + 1;
    } else {
        #pragma unroll
        for (int g = 0; g < NCH; ++g) {
            eo1[g] = 0xffffffffu; ej1[g] = 0xffffffffu;
            if (64 * g < cnt1) {
                const int e = l + 64 * g;
                if (e < cnt1) {
                    const ULL kk = s_key[1][e];
                    eo1[g] = (uint32_t)(kk >> 32);
                    ej1[g] = (uint32_t)(kk & 0xffffffffu);
                }
            }
        }
    }

    if (nd0 || nd1) {
        const uint32_t ORDR2 = 0x80000000u | __float_as_uint(R2);
        // fused dual binary search (independent chains -> in-wave ILP)
        uint32_t lo0 = 0u, hi0 = nd0 ? ORDR2 : 0u;
        uint32_t lo1 = 0u, hi1 = nd1 ? ORDR2 : 0u;
        while ((lo0 < hi0) | (lo1 < hi1)) {
            if (lo0 < hi0) {
                const uint32_t mid = lo0 + ((hi0 - lo0) >> 1);
                int c = 0;
                #pragma unroll
                for (int g = 0; g < NCH; ++g)
                    if (64 * g < cnt0) c += __popcll(__ballot(eo0[g] <= mid));
                if (c >= KMAX) hi0 = mid; else lo0 = mid + 1;
            }
            if (lo1 < hi1) {
                const uint32_t mid = lo1 + ((hi1 - lo1) >> 1);
                int c = 0;
                #pragma unroll
                for (int g = 0; g < NCH; ++g)
                    if (64 * g < cnt1) c += __popcll(__ballot(eo1[g] <= mid));
                if (c >= KMAX) hi1 = mid; else lo1 = mid + 1;
            }
        }
        const uint32_t T0 = lo0, T1 = lo1;

        int cLT0 = 0, cLE0 = 0, cLT1 = 0, cLE1 = 0;
        if (nd0) {
            #pragma unroll
            for (int g = 0; g < NCH; ++g) {
                cLT0 += __popcll(__ballot(eo0[g] < T0));
                cLE0 += __popcll(__ballot(eo0[g] <= T0));
            }
        }
        if (nd1) {
            #pragma unroll
            for (int g = 0; g < NCH; ++g) {
                cLT1 += __popcll(__ballot(eo1[g] < T1));
                cLE1 += __popcll(__ballot(eo1[g] <= T1));
            }
        }

        // tie resolution on j (exact; rarely taken)
        uint32_t J0 = 0xffffffffu, J1 = 0xffffffffu;
        const bool tb0 = nd0 && (cLE0 > KMAX), tb1 = nd1 && (cLE1 > KMAX);
        if (tb0 | tb1) {
            uint32_t jlo0 = 0u, jhi0 = tb0 ? (NPTS - 1) : 0u;
            uint32_t jlo1 = 0u, jhi1 = tb1 ? (NPTS - 1) : 0u;
            const int need0 = KMAX - cLT0, need1 = KMAX - cLT1;
            while ((jlo0 < jhi0) | (jlo1 < jhi1)) {
                if (jlo0 < jhi0) {
                    const uint32_t jmid = jlo0 + ((jhi0 - jlo0) >> 1);
                    int c = 0;
                    #pragma unroll
                    for (int g = 0; g < NCH; ++g)
                        if (64 * g < cnt0) c += __popcll(__ballot(eo0[g] == T0 && ej0[g] <= jmid));
                    if (c >= need0) jhi0 = jmid; else jlo0 = jmid + 1;
                }
                if (jlo1 < jhi1) {
                    const uint32_t jmid = jlo1 + ((jhi1 - jlo1) >> 1);
                    int c = 0;
                    #pragma unroll
                    for (int g = 0; g < NCH; ++g)
                        if (64 * g < cnt1) c += __popcll(__ballot(eo1[g] == T1 && ej1[g] <= jmid));
                    if (c >= need1) jhi1 = jmid; else jlo1 = jmid + 1;
                }
            }
            if (tb0) J0 = jlo0;
            if (tb1) J1 = jlo1;
        }

        // ballot-compact selected sets (order irrelevant for max-agg)
        if (nd0) {
            int sb = 0;
            #pragma unroll
            for (int g = 0; g < NCH; ++g) {
                if (64 * g < cnt0) {
                    const bool take = (eo0[g] < T0) || ((eo0[g] == T0) && (ej0[g] <= J0));
                    const ULL mk = __ballot(take);
                    if (take) nbr[(size_t)i0 * KMAX + sb + __popcll(mk & lmask)] = (int)ej0[g];
                    sb += __popcll(mk);
                }
            }
        }
        if (nd1) {
            int sb = 0;
            #pragma unroll
            for (int g = 0; g < NCH; ++g) {
                if (64 * g < cnt1) {
                    const bool take = (eo1[g] < T1) || ((eo1[g] == T1) && (ej1[g] <= J1));
                    const ULL mk = __ballot(take);
                    if (take) nbr[(size_t)(i0 + 1) * KMAX + sb + __popcll(mk & lmask)] = (int)ej1[g];
                    sb += __popcll(mk);
                }
            }
        }
    }
}

// ---- phase 2: 1 wave = 2 centroids, no LDS, uniform work:
//      af build from A/nbr -> shared-B MFMA -> masked max -> out ----
__global__ __launch_bounds__(64, 4) void mfma_kernel(
    const unsigned short* __restrict__ W2T, const float* __restrict__ b2,
    const float* __restrict__ A, const float* __restrict__ C,
    const int* __restrict__ nbr, const int* __restrict__ mcnt,
    float* __restrict__ out)
{
    const int l  = threadIdx.x;
    const int i0 = blockIdx.x * 2;
    const int r = l & 15, q = l >> 4;

    const int mm[2] = { mcnt[i0], mcnt[i0 + 1] };

    bf16x8 af[2][4][2];
    #pragma unroll
    for (int ci = 0; ci < 2; ++ci) {
        const int iw = i0 + ci;
        float cv[2][8];
        {
            const float4* Cv = (const float4*)(C + (size_t)iw * HID1);
            #pragma unroll
            for (int kc = 0; kc < 2; ++kc) {
                const float4 c0 = Cv[kc * 8 + q * 2], c1 = Cv[kc * 8 + q * 2 + 1];
                cv[kc][0] = c0.x; cv[kc][1] = c0.y; cv[kc][2] = c0.z; cv[kc][3] = c0.w;
                cv[kc][4] = c1.x; cv[kc][5] = c1.y; cv[kc][6] = c1.z; cv[kc][7] = c1.w;
            }
        }
        #pragma unroll
        for (int t = 0; t < 4; ++t) {
            const int row = t * 16 + r;
            const int j = nbr[(size_t)iw * KMAX + row];   // valid even for row >= m
            const float4* Aj = (const float4*)(A + (size_t)j * HID1);
            #pragma unroll
            for (int kc = 0; kc < 2; ++kc) {
                const float4 a0 = Aj[kc * 8 + q * 2], a1 = Aj[kc * 8 + q * 2 + 1];
                bf16x8 v;
                v[0] = f2bf(fmaxf(a0.x - cv[kc][0], 0.0f));
                v[1] = f2bf(fmaxf(a0.y - cv[kc][1], 0.0f));
                v[2] = f2bf(fmaxf(a0.z - cv[kc][2], 0.0f));
                v[3] = f2bf(fmaxf(a0.w - cv[kc][3], 0.0f));
                v[4] = f2bf(fmaxf(a1.x - cv[kc][4], 0.0f));
                v[5] = f2bf(fmaxf(a1.y - cv[kc][5], 0.0f));
                v[6] = f2bf(fmaxf(a1.z - cv[kc][6], 0.0f));
                v[7] = f2bf(fmaxf(a1.w - cv[kc][7], 0.0f));
                af[ci][t][kc] = v;
            }
        }
    }

    // per col-tile: one B-fragment load feeds both centroids (16 MFMA / load)
    #pragma unroll
    for (int cb = 0; cb < 8; ++cb) {
        f32x4 acc[2][4];
        #pragma unroll
        for (int ci = 0; ci < 2; ++ci)
            #pragma unroll
            for (int t = 0; t < 4; ++t) acc[ci][t] = (f32x4){0.f, 0.f, 0.f, 0.f};

        #pragma unroll
        for (int kc = 0; kc < 2; ++kc) {
            const bf16x8 bf =
                *(const bf16x8*)&W2T[(cb * 16 + r) * HID1 + kc * 32 + q * 8];
            #pragma unroll
            for (int ci = 0; ci < 2; ++ci)
                #pragma unroll
                for (int t = 0; t < 4; ++t)
                    acc[ci][t] = __builtin_amdgcn_mfma_f32_16x16x32_bf16(
                        af[ci][t][kc], bf, acc[ci][t], 0, 0, 0);
        }

        const int c = cb * 16 + r;
        #pragma unroll
        for (int ci = 0; ci < 2; ++ci) {
            float v = -FLT_MAX;
            #pragma unroll
            for (int t = 0; t < 4; ++t) {
                const int nb = t * 16 + q * 4;   // D: col=l&15, row=(l>>4)*4+reg
                #pragma unroll
                for (int reg = 0; reg < 4; ++reg)
                    if (nb + reg < mm[ci]) v = fmaxf(v, acc[ci][t][reg]);
            }
            v = fmaxf(v, __shfl_xor(v, 16));
            v = fmaxf(v, __shfl_xor(v, 32));
            if (q == 0)
                out[(size_t)(i0 + ci) * HID2 + c] = fmaxf(v + b2[c], 0.0f);
        }
    }
}

extern "C" void kernel_launch(void* const* d_in, const int* in_sizes, int n_in,
                              void* d_out, int out_size, void* d_ws, size_t ws_size,
                              hipStream_t stream) {
    const float* x     = (const float*)d_in[0];
    const float* pos   = (const float*)d_in[1];
    const int*   batch = (const int*)d_in[2];
    const float* W1    = (const float*)d_in[3];
    const float* b1    = (const float*)d_in[4];
    const float* W2    = (const float*)d_in[5];
    const float* b2    = (const float*)d_in[6];
    float* out = (float*)d_out;

    float*  A    = (float*)d_ws;                          // 2 MB
    float*  C    = A + (size_t)NPTS * HID1;               // 2 MB
    float4* P4   = (float4*)(C + (size_t)NPTS * HID1);    // 128 KB
    unsigned short* W2T = (unsigned short*)(P4 + NPTS);   // 16 KB
    int* nbr  = (int*)(W2T + HID1 * HID2);                // 2 MB
    int* mcnt = nbr + (size_t)NPTS * KMAX;                // 32 KB

    hipLaunchKernelGGL(prep_kernel, dim3(NPTS * HID1 / 256), dim3(256), 0, stream,
                       x, pos, batch, W1, b1, W2, A, C, P4, W2T, out);
    hipLaunchKernelGGL(select_kernel, dim3(NPTS / 2), dim3(64), 0, stream,
                       batch, P4, nbr, mcnt);
    hipLaunchKernelGGL(mfma_kernel, dim3(NPTS / 2), dim3(64), 0, stream,
                       W2T, b2, A, C, nbr, mcnt, out);
}

// Round 16
// 49.232 us; speedup vs baseline: 2.3700x; 1.3364x over previous
//
#include <hip/hip_runtime.h>
#include <hip/hip_bf16.h>
#include <float.h>
#include <stdint.h>

#define NPTS 8192
#define SEG  2048
#define CF   16
#define HID1 64
#define HID2 128
#define KMAX 64
#define R2   0.49f
#define CAP  384          // max in-radius candidates ~170 expected; wide margin
#define NCH  6            // CAP / 64

typedef unsigned long long ULL;
typedef short bf16x8 __attribute__((ext_vector_type(8)));
typedef float f32x4  __attribute__((ext_vector_type(4)));

__device__ __forceinline__ uint32_t f2ord(float f) {
    uint32_t u = __float_as_uint(f);
    return (u & 0x80000000u) ? ~u : (u | 0x80000000u);
}

// native RNE f32 -> bf16 (hardware v_cvt; identical bits to manual RNE for finite)
__device__ __forceinline__ short f2bf(float f) {
    __hip_bfloat16 h = __float2bfloat16(f);
    union { __hip_bfloat16 b; short s; } u; u.b = h;
    return u.s;
}

// ---- prep: A = x@W1[:16] + pos@W1[16:19] + b1 ; C = pos@W1[16:19] ;
//      pos4 = (x,y,z,sq) ; W2T[c][k] = bf16(W2[k][c]) ; echo pos/batch ----
__global__ __launch_bounds__(256) void prep_kernel(
    const float* __restrict__ x, const float* __restrict__ pos,
    const int* __restrict__ batch,
    const float* __restrict__ W1, const float* __restrict__ b1,
    const float* __restrict__ W2,
    float* __restrict__ A, float* __restrict__ C,
    float4* __restrict__ pos4, unsigned short* __restrict__ W2T,
    float* __restrict__ out)
{
    const int t = blockIdx.x * 256 + threadIdx.x;   // t < NPTS*64
    const int i = t >> 6, k = t & 63;

    const float px = pos[3 * i + 0], py = pos[3 * i + 1], pz = pos[3 * i + 2];
    float c = __fmul_rn(px, W1[16 * HID1 + k]);
    c = fmaf(py, W1[17 * HID1 + k], c);
    c = fmaf(pz, W1[18 * HID1 + k], c);

    float a = b1[k];
    #pragma unroll
    for (int cc = 0; cc < CF; ++cc)
        a = fmaf(x[i * CF + cc], W1[cc * HID1 + k], a);
    a += c;

    A[t] = a;
    C[t] = c;

    if (t < HID1 * HID2) {
        const int cc = t >> 6, kk = t & 63;      // W2T[c][k], c-stride 64
        W2T[t] = (unsigned short)f2bf(W2[kk * HID2 + cc]);
    }

    if (k == 0) {
        const float sq = __fadd_rn(__fadd_rn(__fmul_rn(px, px), __fmul_rn(py, py)),
                                   __fmul_rn(pz, pz));
        pos4[i] = make_float4(px, py, pz, sq);
    }
    if (k < 3) out[NPTS * HID2 + 3 * i + k] = pos[3 * i + k];
    if (k == 3) out[NPTS * HID2 + NPTS * 3 + i] = (float)batch[i];
}

// ---- 1 wave = 2 centroids: hoisted cv loads -> prefetched shared-load scan ->
//      fused dual threshold select -> hoisted dual af build -> shared-B MFMA ----
__global__ __launch_bounds__(64, 3) void pointconv_kernel(
    const int* __restrict__ batch,
    const unsigned short* __restrict__ W2T, const float* __restrict__ b2,
    const float* __restrict__ A, const float* __restrict__ C,
    const float4* __restrict__ pos4, float* __restrict__ out)
{
    __shared__ ULL s_key[2][CAP];   // 6 KB
    __shared__ int s_nbr[2][KMAX];  // 512 B

    const int l  = threadIdx.x;
    const int i0 = blockIdx.x * 2;          // pair shares a segment (2048 even)
    const int r = l & 15, q = l >> 4;

    const float4 cw0 = pos4[i0], cw1 = pos4[i0 + 1];
    const int seg0 = batch[i0] * SEG;
    const ULL lmask = (1ull << l) - 1ull;

    // hoisted C-row loads (independent of everything below; overlap with scan)
    float cv[2][2][8];
    #pragma unroll
    for (int ci = 0; ci < 2; ++ci) {
        const float4* Cv = (const float4*)(C + (size_t)(i0 + ci) * HID1);
        #pragma unroll
        for (int kc = 0; kc < 2; ++kc) {
            const float4 c0 = Cv[kc * 8 + q * 2], c1 = Cv[kc * 8 + q * 2 + 1];
            cv[ci][kc][0] = c0.x; cv[ci][kc][1] = c0.y;
            cv[ci][kc][2] = c0.z; cv[ci][kc][3] = c0.w;
            cv[ci][kc][4] = c1.x; cv[ci][kc][5] = c1.y;
            cv[ci][kc][6] = c1.z; cv[ci][kc][7] = c1.w;
        }
    }

    // shared-load scan with one-iteration-ahead register prefetch
    int cnt0 = 0, cnt1 = 0;
    float4 pj = pos4[seg0 + l];
    #pragma unroll 4
    for (int it = 0; it < SEG / 64; ++it) {
        const float4 cur = pj;
        if (it + 1 < SEG / 64) pj = pos4[seg0 + (it + 1) * 64 + l];
        const int j = seg0 + it * 64 + l;
        const float dot0 = fmaf(cw0.z, cur.z, fmaf(cw0.y, cur.y, __fmul_rn(cw0.x, cur.x)));
        const float d20  = __fsub_rn(__fadd_rn(cw0.w, cur.w), __fmul_rn(2.0f, dot0));
        const float dot1 = fmaf(cw1.z, cur.z, fmaf(cw1.y, cur.y, __fmul_rn(cw1.x, cur.x)));
        const float d21  = __fsub_rn(__fadd_rn(cw1.w, cur.w), __fmul_rn(2.0f, dot1));
        const bool h0 = (d20 <= R2), h1 = (d21 <= R2);
        const ULL m0 = __ballot(h0), m1 = __ballot(h1);
        if (h0) {
            const int p = cnt0 + __popcll(m0 & lmask);
            if (p < CAP) s_key[0][p] = ((ULL)f2ord(d20) << 32) | (unsigned)j;
        }
        cnt0 += __popcll(m0);
        if (h1) {
            const int p = cnt1 + __popcll(m1 & lmask);
            if (p < CAP) s_key[1][p] = ((ULL)f2ord(d21) << 32) | (unsigned)j;
        }
        cnt1 += __popcll(m1);
    }
    if (cnt0 > CAP) cnt0 = CAP;
    if (cnt1 > CAP) cnt1 = CAP;
    const bool nd0 = cnt0 > KMAX, nd1 = cnt1 > KMAX;

    uint32_t eo0[NCH], ej0[NCH], eo1[NCH], ej1[NCH];
    if (!nd0) {
        if (l < KMAX) s_nbr[0][l] = (l < cnt0) ? (int)(s_key[0][l] & 0xffffffffu) : i0;
    } else {
        #pragma unroll
        for (int g = 0; g < NCH; ++g) {
            eo0[g] = 0xffffffffu; ej0[g] = 0xffffffffu;
            if (64 * g < cnt0) {
                const int e = l + 64 * g;
                if (e < cnt0) {
                    const ULL kk = s_key[0][e];
                    eo0[g] = (uint32_t)(kk >> 32);
                    ej0[g] = (uint32_t)(kk & 0xffffffffu);
                }
            }
        }
    }
    if (!nd1) {
        if (l < KMAX) s_nbr[1][l] = (l < cnt1) ? (int)(s_key[1][l] & 0xffffffffu) : i0 + 1;
    } else {
        #pragma unroll
        for (int g = 0; g < NCH; ++g) {
            eo1[g] = 0xffffffffu; ej1[g] = 0xffffffffu;
            if (64 * g < cnt1) {
                const int e = l + 64 * g;
                if (e < cnt1) {
                    const ULL kk = s_key[1][e];
                    eo1[g] = (uint32_t)(kk >> 32);
                    ej1[g] = (uint32_t)(kk & 0xffffffffu);
                }
            }
        }
    }

    if (nd0 || nd1) {
        const uint32_t ORDR2 = 0x80000000u | __float_as_uint(R2);
        // fused dual binary search (independent chains -> in-wave ILP)
        uint32_t lo0 = 0u, hi0 = nd0 ? ORDR2 : 0u;
        uint32_t lo1 = 0u, hi1 = nd1 ? ORDR2 : 0u;
        while ((lo0 < hi0) | (lo1 < hi1)) {
            if (lo0 < hi0) {
                const uint32_t mid = lo0 + ((hi0 - lo0) >> 1);
                int c = 0;
                #pragma unroll
                for (int g = 0; g < NCH; ++g)
                    if (64 * g < cnt0) c += __popcll(__ballot(eo0[g] <= mid));
                if (c >= KMAX) hi0 = mid; else lo0 = mid + 1;
            }
            if (lo1 < hi1) {
                const uint32_t mid = lo1 + ((hi1 - lo1) >> 1);
                int c = 0;
                #pragma unroll
                for (int g = 0; g < NCH; ++g)
                    if (64 * g < cnt1) c += __popcll(__ballot(eo1[g] <= mid));
                if (c >= KMAX) hi1 = mid; else lo1 = mid + 1;
            }
        }
        const uint32_t T0 = lo0, T1 = lo1;

        int cLT0 = 0, cLE0 = 0, cLT1 = 0, cLE1 = 0;
        if (nd0) {
            #pragma unroll
            for (int g = 0; g < NCH; ++g) {
                cLT0 += __popcll(__ballot(eo0[g] < T0));
                cLE0 += __popcll(__ballot(eo0[g] <= T0));
            }
        }
        if (nd1) {
            #pragma unroll
            for (int g = 0; g < NCH; ++g) {
                cLT1 += __popcll(__ballot(eo1[g] < T1));
                cLE1 += __popcll(__ballot(eo1[g] <= T1));
            }
        }

        // fused tie resolution on j (exact; rarely taken)
        uint32_t J0 = 0xffffffffu, J1 = 0xffffffffu;
        const bool tb0 = nd0 && (cLE0 > KMAX), tb1 = nd1 && (cLE1 > KMAX);
        if (tb0 | tb1) {
            uint32_t jlo0 = 0u, jhi0 = tb0 ? (NPTS - 1) : 0u;
            uint32_t jlo1 = 0u, jhi1 = tb1 ? (NPTS - 1) : 0u;
            const int need0 = KMAX - cLT0, need1 = KMAX - cLT1;
            while ((jlo0 < jhi0) | (jlo1 < jhi1)) {
                if (jlo0 < jhi0) {
                    const uint32_t jmid = jlo0 + ((jhi0 - jlo0) >> 1);
                    int c = 0;
                    #pragma unroll
                    for (int g = 0; g < NCH; ++g)
                        if (64 * g < cnt0) c += __popcll(__ballot(eo0[g] == T0 && ej0[g] <= jmid));
                    if (c >= need0) jhi0 = jmid; else jlo0 = jmid + 1;
                }
                if (jlo1 < jhi1) {
                    const uint32_t jmid = jlo1 + ((jhi1 - jlo1) >> 1);
                    int c = 0;
                    #pragma unroll
                    for (int g = 0; g < NCH; ++g)
                        if (64 * g < cnt1) c += __popcll(__ballot(eo1[g] == T1 && ej1[g] <= jmid));
                    if (c >= need1) jhi1 = jmid; else jlo1 = jmid + 1;
                }
            }
            if (tb0) J0 = jlo0;
            if (tb1) J1 = jlo1;
        }

        // ballot-compact selected sets (order irrelevant for max-agg)
        if (nd0) {
            int sb = 0;
            #pragma unroll
            for (int g = 0; g < NCH; ++g) {
                if (64 * g < cnt0) {
                    const bool take = (eo0[g] < T0) || ((eo0[g] == T0) && (ej0[g] <= J0));
                    const ULL mk = __ballot(take);
                    if (take) s_nbr[0][sb + __popcll(mk & lmask)] = (int)ej0[g];
                    sb += __popcll(mk);
                }
            }
        }
        if (nd1) {
            int sb = 0;
            #pragma unroll
            for (int g = 0; g < NCH; ++g) {
                if (64 * g < cnt1) {
                    const bool take = (eo1[g] < T1) || ((eo1[g] == T1) && (ej1[g] <= J1));
                    const ULL mk = __ballot(take);
                    if (take) s_nbr[1][sb + __popcll(mk & lmask)] = (int)ej1[g];
                    sb += __popcll(mk);
                }
            }
        }
    }

    // ---- MFMA phase: hoisted dual af build, then shared-B MFMA ----
    const int mm[2] = { cnt0 < KMAX ? cnt0 : KMAX, cnt1 < KMAX ? cnt1 : KMAX };

    bf16x8 af[2][4][2];
    #pragma unroll
    for (int ci = 0; ci < 2; ++ci) {
        #pragma unroll
        for (int t = 0; t < 4; ++t) {
            const int row = t * 16 + r;
            const int j = s_nbr[ci][row];      // valid index even for row >= m
            const float4* Aj = (const float4*)(A + (size_t)j * HID1);
            #pragma unroll
            for (int kc = 0; kc < 2; ++kc) {
                const float4 a0 = Aj[kc * 8 + q * 2], a1 = Aj[kc * 8 + q * 2 + 1];
                bf16x8 v;
                v[0] = f2bf(fmaxf(a0.x - cv[ci][kc][0], 0.0f));
                v[1] = f2bf(fmaxf(a0.y - cv[ci][kc][1], 0.0f));
                v[2] = f2bf(fmaxf(a0.z - cv[ci][kc][2], 0.0f));
                v[3] = f2bf(fmaxf(a0.w - cv[ci][kc][3], 0.0f));
                v[4] = f2bf(fmaxf(a1.x - cv[ci][kc][4], 0.0f));
                v[5] = f2bf(fmaxf(a1.y - cv[ci][kc][5], 0.0f));
                v[6] = f2bf(fmaxf(a1.z - cv[ci][kc][6], 0.0f));
                v[7] = f2bf(fmaxf(a1.w - cv[ci][kc][7], 0.0f));
                af[ci][t][kc] = v;
            }
        }
    }

    // per col-tile: one B-fragment load feeds both centroids (16 MFMA / load)
    #pragma unroll
    for (int cb = 0; cb < 8; ++cb) {
        f32x4 acc[2][4];
        #pragma unroll
        for (int ci = 0; ci < 2; ++ci)
            #pragma unroll
            for (int t = 0; t < 4; ++t) acc[ci][t] = (f32x4){0.f, 0.f, 0.f, 0.f};

        #pragma unroll
        for (int kc = 0; kc < 2; ++kc) {
            const bf16x8 bf =
                *(const bf16x8*)&W2T[(cb * 16 + r) * HID1 + kc * 32 + q * 8];
            #pragma unroll
            for (int ci = 0; ci < 2; ++ci)
                #pragma unroll
                for (int t = 0; t < 4; ++t)
                    acc[ci][t] = __builtin_amdgcn_mfma_f32_16x16x32_bf16(
                        af[ci][t][kc], bf, acc[ci][t], 0, 0, 0);
        }

        const int c = cb * 16 + r;
        #pragma unroll
        for (int ci = 0; ci < 2; ++ci) {
            float v = -FLT_MAX;
            #pragma unroll
            for (int t = 0; t < 4; ++t) {
                const int nb = t * 16 + q * 4; // D: col=l&15, row=(l>>4)*4+reg
                #pragma unroll
                for (int reg = 0; reg < 4; ++reg)
                    if (nb + reg < mm[ci]) v = fmaxf(v, acc[ci][t][reg]);
            }
            v = fmaxf(v, __shfl_xor(v, 16));
            v = fmaxf(v, __shfl_xor(v, 32));
            if (q == 0)
                out[(size_t)(i0 + ci) * HID2 + c] = fmaxf(v + b2[c], 0.0f);
        }
    }
}

extern "C" void kernel_launch(void* const* d_in, const int* in_sizes, int n_in,
                              void* d_out, int out_size, void* d_ws, size_t ws_size,
                              hipStream_t stream) {
    const float* x     = (const float*)d_in[0];
    const float* pos   = (const float*)d_in[1];
    const int*   batch = (const int*)d_in[2];
    const float* W1    = (const float*)d_in[3];
    const float* b1    = (const float*)d_in[4];
    const float* W2    = (const float*)d_in[5];
    const float* b2    = (const float*)d_in[6];
    float* out = (float*)d_out;

    float*  A    = (float*)d_ws;                          // 2 MB
    float*  C    = A + (size_t)NPTS * HID1;               // 2 MB
    float4* P4   = (float4*)(C + (size_t)NPTS * HID1);    // 128 KB (16B aligned)
    unsigned short* W2T = (unsigned short*)(P4 + NPTS);   // 16 KB

    hipLaunchKernelGGL(prep_kernel, dim3(NPTS * HID1 / 256), dim3(256), 0, stream,
                       x, pos, batch, W1, b1, W2, A, C, P4, W2T, out);
    hipLaunchKernelGGL(pointconv_kernel, dim3(NPTS / 2), dim3(64), 0, stream,
                       batch, W2T, b2, A, C, P4, out);
}